// Round 16
// baseline (362.979 us; speedup 1.0000x reference)
//
#include <hip/hip_runtime.h>
#include <hip/hip_bf16.h>

#define C_NUM 100000
#define D_EMB 512
#define N_BATCH 512
#define SCALE_F 30.0f
#define MARGIN_F 0.4f
#define H_F 0.333f
#define NT2 782              // ceil(100000/128) class tiles
#define PST 784              // padded partial stride (per row)

typedef __attribute__((ext_vector_type(8))) short bf16x8;
typedef __attribute__((ext_vector_type(4))) short bf16x4;
typedef __attribute__((ext_vector_type(4))) float f32x4;
typedef __attribute__((ext_vector_type(16))) float f32x16;

static __device__ __forceinline__ short f2bf(float f) {
  __hip_bfloat16 h = __float2bfloat16(f);
  union { __hip_bfloat16 b; short s; } u;
  u.b = h;
  return u.s;
}

static __device__ __forceinline__ float sq4(f32x4 v) {
  return v[0]*v[0] + v[1]*v[1] + v[2]*v[2] + v[3]*v[3];
}

// async global -> LDS: 16 B/lane; dest = wave-uniform base + lane*16
static __device__ __forceinline__ void gload16(const void* g, void* l) {
  __builtin_amdgcn_global_load_lds(
      (const __attribute__((address_space(1))) void*)g,
      (__attribute__((address_space(3))) void*)l, 16, 0, 0);
}

// ---------------------------------------------------------------------------
// Kernel 1: per-row L2 norm of embeddings; unit-normalized rows as bf16.
// ---------------------------------------------------------------------------
__global__ __launch_bounds__(64) void k_rownorm(const float* __restrict__ emb,
                                                short* __restrict__ Aunit,
                                                float* __restrict__ norms) {
  const int i = blockIdx.x;
  const int l = threadIdx.x;
  const f32x4* row = reinterpret_cast<const f32x4*>(emb + (size_t)i * D_EMB);
  f32x4 v0 = row[l];
  f32x4 v1 = row[l + 64];
  float ss = sq4(v0) + sq4(v1);
#pragma unroll
  for (int m = 1; m < 64; m <<= 1) ss += __shfl_xor(ss, m);
  float nrm = sqrtf(ss);
  float inv = 1.0f / nrm;
  bf16x4 o0, o1;
#pragma unroll
  for (int q = 0; q < 4; ++q) { o0[q] = f2bf(v0[q] * inv); o1[q] = f2bf(v1[q] * inv); }
  bf16x4* dst = reinterpret_cast<bf16x4*>(Aunit + (size_t)i * D_EMB);
  dst[l] = o0;
  dst[l + 64] = o1;
  if (l == 0) norms[i] = nrm;
}

// ---------------------------------------------------------------------------
// Kernel 2: batch mean / unbiased std -> adaptive margin per row.
// ---------------------------------------------------------------------------
__global__ __launch_bounds__(512) void k_stats(const float* __restrict__ norms,
                                               float* __restrict__ marg) {
  __shared__ float red[8];
  const int t = threadIdx.x;
  const int lane = t & 63, wid = t >> 6;
  float x = norms[t];
  float s = x;
#pragma unroll
  for (int m = 1; m < 64; m <<= 1) s += __shfl_xor(s, m);
  if (lane == 0) red[wid] = s;
  __syncthreads();
  float tot = 0.f;
#pragma unroll
  for (int q = 0; q < 8; ++q) tot += red[q];
  const float mean = tot / 512.f;
  __syncthreads();
  float d = x - mean;
  float s2 = d * d;
#pragma unroll
  for (int m = 1; m < 64; m <<= 1) s2 += __shfl_xor(s2, m);
  if (lane == 0) red[wid] = s2;
  __syncthreads();
  float tot2 = 0.f;
#pragma unroll
  for (int q = 0; q < 8; ++q) tot2 += red[q];
  const float stdv = sqrtf(tot2 / 511.f);   // ddof=1
  float msc = (x - mean) / (stdv + H_F);
  msc = fminf(1.f, fmaxf(-1.f, msc));
  marg[t] = MARGIN_F * (1.f + msc);
}

// ---------------------------------------------------------------------------
// Kernel 3: barrier-free K-loop.
// - A (128 rows x 512 K bf16, 128 KB) staged ONCE into static LDS
//   (XOR-swizzled source, one vmcnt(16)+barrier), never re-staged.
// - W wave-private: wave w owns 32 classes; 4-deep register pipeline
//   (consume -> cvt+ds_write to private buffer -> wave-local lgkmcnt(0)
//   -> refill issue -> compute). NO s_barrier in the loop.
// - Per wave: 128 rows x 32 cls (4 f32x16 accs). 1 block/CU (LDS 142 KB);
//   512-reg budget -> no spill possible.
// ---------------------------------------------------------------------------
__global__ __launch_bounds__(256) void k_main(const short* __restrict__ Aunit,
                                              const float* __restrict__ weight,
                                              const int* __restrict__ labels,
                                              const float* __restrict__ marg,
                                              float* __restrict__ partial,
                                              float* __restrict__ tlogit) {
  __shared__ alignas(16) char Astat[131072];   // [128 rows][1024 B] bf16, swizzled
  __shared__ alignas(16) char Wsl[4][2816];    // per-wave [32 cls][88 B] bf16
  __shared__ float winv[4][32];
  __shared__ float rowsum[128][4];

  const int bid = blockIdx.x;
  const int grp = bid >> 5, within = bid & 31;
  const int rt = (within >> 3) & 3;            // 0..3
  const int ct = grp * 8 + (within & 7);       // 0..783 (guarded)
  if (ct >= NT2) return;

  const int tid = threadIdx.x;                 // 0..255
  const int w = tid >> 6, lane = tid & 63;
  const int l31 = lane & 31, lhi = lane >> 5;
  const int lhi16 = lhi * 16;
  const int xr = (l31 & 15) << 4;              // A read swizzle (rows mi*32+l31 share it)

  // ---- A static stage: 32 gloads per wave, rows w*32 .. w*32+31 ----
  {
    const char* Asrc = (const char*)Aunit + (size_t)(rt * 128 + w * 32) * 1024;
    char* Adst = &Astat[(w * 32) * 1024];
    const int ls = lane * 16;
#pragma unroll
    for (int i = 0; i < 32; ++i)
      gload16(Asrc + (size_t)i * 1024 + (ls ^ ((i & 15) << 4)), Adst + i * 1024);
  }
  __builtin_amdgcn_sched_barrier(0);

  // ---- W roles: wave-private 32 classes; lane covers (cls = rnd*8 + c8, su) ----
  const int su = lane & 7;       // 8 lanes per class, 16 B f32 each
  const int c8 = lane >> 3;      // 0..7
  const float* wb0; const float* wb1; const float* wb2; const float* wb3;
  int wd0, wd1, wd2, wd3;
  {
    int l0 = w * 32 + 0 * 8 + c8, l1 = w * 32 + 1 * 8 + c8;
    int l2 = w * 32 + 2 * 8 + c8, l3 = w * 32 + 3 * 8 + c8;
    int g0 = ct * 128 + l0; if (g0 > C_NUM - 1) g0 = C_NUM - 1;
    int g1 = ct * 128 + l1; if (g1 > C_NUM - 1) g1 = C_NUM - 1;
    int g2 = ct * 128 + l2; if (g2 > C_NUM - 1) g2 = C_NUM - 1;
    int g3 = ct * 128 + l3; if (g3 > C_NUM - 1) g3 = C_NUM - 1;
    wb0 = weight + (size_t)g0 * D_EMB + su * 4;
    wb1 = weight + (size_t)g1 * D_EMB + su * 4;
    wb2 = weight + (size_t)g2 * D_EMB + su * 4;
    wb3 = weight + (size_t)g3 * D_EMB + su * 4;
    wd0 = (0 * 8 + c8) * 88 + su * 8; wd1 = (1 * 8 + c8) * 88 + su * 8;
    wd2 = (2 * 8 + c8) * 88 + su * 8; wd3 = (3 * 8 + c8) * 88 + su * 8;
  }
  char* Wme = &Wsl[w][0];
  const int bb = l31 * 88 + lhi16;             // b-frag base (2-way banks, free)

  // A read bases (4 row-groups)
  const int ab0 = (0 * 32 + l31) * 1024;
  const int ab1 = (1 * 32 + l31) * 1024;
  const int ab2 = (2 * 32 + l31) * 1024;
  const int ab3 = (3 * 32 + l31) * 1024;

  f32x16 acc0, acc1, acc2, acc3;
#pragma unroll
  for (int q = 0; q < 16; ++q) { acc0[q] = 0.f; acc1[q] = 0.f; acc2[q] = 0.f; acc3[q] = 0.f; }
  float sq0 = 0.f, sq1 = 0.f, sq2 = 0.f, sq3 = 0.f;

  // 4 in-flight W sets (chunks c, c+1, c+2, c+3), 16 f32x4 = 64 regs
  f32x4 pA0, pA1, pA2, pA3;
  f32x4 pB0, pB1, pB2, pB3;
  f32x4 pC0, pC1, pC2, pC3;
  f32x4 pD0, pD1, pD2, pD3;

#define WLOADSET(S0,S1,S2,S3,OFF) { \
    S0 = *(const f32x4*)(wb0 + (OFF)); S1 = *(const f32x4*)(wb1 + (OFF)); \
    S2 = *(const f32x4*)(wb2 + (OFF)); S3 = *(const f32x4*)(wb3 + (OFF)); }

#define PHASE(S0,S1,S2,S3,C) { \
    sq0 += sq4(S0); sq1 += sq4(S1); sq2 += sq4(S2); sq3 += sq4(S3); \
    { bf16x4 t0, t1, t2, t3; \
      _Pragma("unroll") \
      for (int e = 0; e < 4; ++e) { t0[e] = f2bf(S0[e]); t1[e] = f2bf(S1[e]); \
                                    t2[e] = f2bf(S2[e]); t3[e] = f2bf(S3[e]); } \
      *(bf16x4*)(Wme + wd0) = t0; *(bf16x4*)(Wme + wd1) = t1; \
      *(bf16x4*)(Wme + wd2) = t2; *(bf16x4*)(Wme + wd3) = t3; } \
    asm volatile("s_waitcnt lgkmcnt(0)" ::: "memory"); \
    __builtin_amdgcn_sched_barrier(0); \
    { int nc = (C) + 4; if (nc > 15) nc = 15; \
      WLOADSET(S0, S1, S2, S3, nc * 32); } \
    _Pragma("unroll") \
    for (int kk = 0; kk < 2; ++kk) { \
      const int ka = (((C) * 64 + kk * 32 + lhi16) ^ xr); \
      bf16x8 a0 = *(const bf16x8*)(Astat + ab0 + ka); \
      bf16x8 a1 = *(const bf16x8*)(Astat + ab1 + ka); \
      bf16x8 a2 = *(const bf16x8*)(Astat + ab2 + ka); \
      bf16x8 a3 = *(const bf16x8*)(Astat + ab3 + ka); \
      bf16x8 b  = *(const bf16x8*)(Wme + bb + kk * 32); \
      acc0 = __builtin_amdgcn_mfma_f32_32x32x16_bf16(a0, b, acc0, 0, 0, 0); \
      acc1 = __builtin_amdgcn_mfma_f32_32x32x16_bf16(a1, b, acc1, 0, 0, 0); \
      acc2 = __builtin_amdgcn_mfma_f32_32x32x16_bf16(a2, b, acc2, 0, 0, 0); \
      acc3 = __builtin_amdgcn_mfma_f32_32x32x16_bf16(a3, b, acc3, 0, 0, 0); \
    } }

  // ---- prologue: W sets for chunks 0..3 (A gloads are older -> vmcnt(16)) ----
  WLOADSET(pA0, pA1, pA2, pA3, 0);
  WLOADSET(pB0, pB1, pB2, pB3, 32);
  WLOADSET(pC0, pC1, pC2, pC3, 64);
  WLOADSET(pD0, pD1, pD2, pD3, 96);
  __builtin_amdgcn_sched_barrier(0);
  asm volatile("s_waitcnt vmcnt(16)" ::: "memory");   // all 32 A gloads landed
  __builtin_amdgcn_s_barrier();                        // A visible to all waves
  __builtin_amdgcn_sched_barrier(0);

  // ---- barrier-free K-loop: 16 chunks, unrolled by 4 ----
#pragma unroll
  for (int i = 0; i < 4; ++i) {
    PHASE(pA0, pA1, pA2, pA3, 4 * i + 0);
    PHASE(pB0, pB1, pB2, pB3, 4 * i + 1);
    PHASE(pC0, pC1, pC2, pC3, 4 * i + 2);
    PHASE(pD0, pD1, pD2, pD3, 4 * i + 3);
  }

  // ---- per-class 1/||w|| (wave-private) ----
  {
    float s0 = sq0, s1 = sq1, s2 = sq2, s3 = sq3;
#pragma unroll
    for (int m = 1; m < 8; m <<= 1) {
      s0 += __shfl_xor(s0, m); s1 += __shfl_xor(s1, m);
      s2 += __shfl_xor(s2, m); s3 += __shfl_xor(s3, m);
    }
    if (su == 0) {
      winv[w][0 * 8 + c8]  = (s0 > 0.f) ? rsqrtf(s0) : 0.f;
      winv[w][1 * 8 + c8]  = (s1 > 0.f) ? rsqrtf(s1) : 0.f;
      winv[w][2 * 8 + c8]  = (s2 > 0.f) ? rsqrtf(s2) : 0.f;
      winv[w][3 * 8 + c8]  = (s3 > 0.f) ? rsqrtf(s3) : 0.f;
    }
  }
  asm volatile("s_waitcnt lgkmcnt(0)" ::: "memory");
  __builtin_amdgcn_sched_barrier(0);
  const float wv = winv[w][l31];

  // ---- epilogue: margin at label, per-row exp sums over this wave's 32 cls ----
  // C/D layout: col = lane&31, row = (reg&3) + 8*(reg>>2) + 4*(lane>>5)
  const int gcc = ct * 128 + w * 32 + l31;
  const bool ok = gcc < C_NUM;
#pragma unroll
  for (int mi = 0; mi < 4; ++mi) {
#pragma unroll
    for (int r = 0; r < 16; ++r) {
      const int rowf = (r & 3) + 8 * (r >> 2) + 4 * lhi;
      const int rloc = mi * 32 + rowf;
      const int R = rt * 128 + rloc;
      const float av = (mi == 0) ? acc0[r] : (mi == 1) ? acc1[r] : (mi == 2) ? acc2[r] : acc3[r];
      const float cosv = av * wv;
      float lg = SCALE_F * cosv;
      if (labels[R] == gcc) {
        float ctv = fminf(1.f, fmaxf(-1.f, cosv));
        float lt = SCALE_F * cosf(acosf(ctv) + marg[R]);
        lg = lt;
        tlogit[R] = lt;
      }
      float v = ok ? __expf(lg) : 0.f;
      v += __shfl_xor(v, 1);
      v += __shfl_xor(v, 2);
      v += __shfl_xor(v, 4);
      v += __shfl_xor(v, 8);
      v += __shfl_xor(v, 16);
      if (l31 == 0) rowsum[rloc][w] = v;
    }
  }
  __syncthreads();
  if (tid < 128)
    partial[(size_t)(rt * 128 + tid) * PST + ct] =
        (rowsum[tid][0] + rowsum[tid][1]) + (rowsum[tid][2] + rowsum[tid][3]);
#undef WLOADSET
#undef PHASE
}

// ---------------------------------------------------------------------------
// Kernel 4: per-row reduce (coalesced): term[r] = log(sum_ct partial[r][ct]) - tlogit[r]
// ---------------------------------------------------------------------------
__global__ __launch_bounds__(64) void k_reduce(const float* __restrict__ partial,
                                               const float* __restrict__ tlogit,
                                               float* __restrict__ term) {
  const int r = blockIdx.x;
  const int l = threadIdx.x;
  const float* row = partial + (size_t)r * PST;
  float s = 0.f;
  for (int b = l; b < NT2; b += 64)
    s += row[b];
#pragma unroll
  for (int m = 1; m < 64; m <<= 1) s += __shfl_xor(s, m);
  if (l == 0) term[r] = logf(s) - tlogit[r];
}

// ---------------------------------------------------------------------------
// Kernel 5: loss = mean(term)
// ---------------------------------------------------------------------------
__global__ __launch_bounds__(512) void k_final(const float* __restrict__ term,
                                               float* __restrict__ out) {
  __shared__ float red[8];
  const int t = threadIdx.x;
  const int lane = t & 63, wid = t >> 6;
  float v = term[t];
#pragma unroll
  for (int m = 1; m < 64; m <<= 1) v += __shfl_xor(v, m);
  if (lane == 0) red[wid] = v;
  __syncthreads();
  if (t == 0) {
    float tot = 0.f;
#pragma unroll
    for (int q = 0; q < 8; ++q) tot += red[q];
    out[0] = tot / 512.f;
  }
}

extern "C" void kernel_launch(void* const* d_in, const int* in_sizes, int n_in,
                              void* d_out, int out_size, void* d_ws, size_t ws_size,
                              hipStream_t stream) {
  const float* emb    = (const float*)d_in[0];
  const int*   labels = (const int*)d_in[1];
  const float* weight = (const float*)d_in[2];
  float* out = (float*)d_out;

  char* ws = (char*)d_ws;
  short* Aunit   = (short*)ws;                        // 512*512*2 = 524288 B
  float* norms   = (float*)(ws + 524288);             // 2 KiB
  float* marg    = (float*)(ws + 524288 + 2048);      // 2 KiB
  float* tlog    = (float*)(ws + 524288 + 4096);      // 2 KiB
  float* term    = (float*)(ws + 524288 + 6144);      // 2 KiB
  float* partial = (float*)(ws + 524288 + 8192);      // 512*784*4 = 1605632 B

  k_rownorm<<<N_BATCH, 64, 0, stream>>>(emb, Aunit, norms);
  k_stats<<<1, 512, 0, stream>>>(norms, marg);
  k_main<<<98 * 32, 256, 0, stream>>>(Aunit, weight, labels, marg, partial, tlog);
  k_reduce<<<N_BATCH, 64, 0, stream>>>(partial, tlog, term);
  k_final<<<1, 512, 0, stream>>>(term, out);
}

// Round 17
// 158.867 us; speedup vs baseline: 2.2848x; 2.2848x over previous
//
#include <hip/hip_runtime.h>
#include <hip/hip_bf16.h>

#define C_NUM 100000
#define D_EMB 512
#define N_BATCH 512
#define SCALE_F 30.0f
#define MARGIN_F 0.4f
#define H_F 0.333f
#define NT2 782              // ceil(100000/128) class tiles
#define PST 784              // padded partial stride (per row)

typedef __attribute__((ext_vector_type(8))) short bf16x8;
typedef __attribute__((ext_vector_type(4))) short bf16x4;
typedef __attribute__((ext_vector_type(4))) float f32x4;
typedef __attribute__((ext_vector_type(16))) float f32x16;

static __device__ __forceinline__ short f2bf(float f) {
  __hip_bfloat16 h = __float2bfloat16(f);
  union { __hip_bfloat16 b; short s; } u;
  u.b = h;
  return u.s;
}

static __device__ __forceinline__ float sq4(f32x4 v) {
  return v[0]*v[0] + v[1]*v[1] + v[2]*v[2] + v[3]*v[3];
}

// async global -> LDS: 16 B/lane; dest = wave-uniform base + lane*16
static __device__ __forceinline__ void gload16(const void* g, void* l) {
  __builtin_amdgcn_global_load_lds(
      (const __attribute__((address_space(1))) void*)g,
      (__attribute__((address_space(3))) void*)l, 16, 0, 0);
}

// ---------------------------------------------------------------------------
// Kernel 1: per-row L2 norm of embeddings; unit-normalized rows as bf16.
// ---------------------------------------------------------------------------
__global__ __launch_bounds__(64) void k_rownorm(const float* __restrict__ emb,
                                                short* __restrict__ Aunit,
                                                float* __restrict__ norms) {
  const int i = blockIdx.x;
  const int l = threadIdx.x;
  const f32x4* row = reinterpret_cast<const f32x4*>(emb + (size_t)i * D_EMB);
  f32x4 v0 = row[l];
  f32x4 v1 = row[l + 64];
  float ss = sq4(v0) + sq4(v1);
#pragma unroll
  for (int m = 1; m < 64; m <<= 1) ss += __shfl_xor(ss, m);
  float nrm = sqrtf(ss);
  float inv = 1.0f / nrm;
  bf16x4 o0, o1;
#pragma unroll
  for (int q = 0; q < 4; ++q) { o0[q] = f2bf(v0[q] * inv); o1[q] = f2bf(v1[q] * inv); }
  bf16x4* dst = reinterpret_cast<bf16x4*>(Aunit + (size_t)i * D_EMB);
  dst[l] = o0;
  dst[l + 64] = o1;
  if (l == 0) norms[i] = nrm;
}

// ---------------------------------------------------------------------------
// Kernel 2: batch mean / unbiased std -> adaptive margin per row.
// ---------------------------------------------------------------------------
__global__ __launch_bounds__(512) void k_stats(const float* __restrict__ norms,
                                               float* __restrict__ marg) {
  __shared__ float red[8];
  const int t = threadIdx.x;
  const int lane = t & 63, wid = t >> 6;
  float x = norms[t];
  float s = x;
#pragma unroll
  for (int m = 1; m < 64; m <<= 1) s += __shfl_xor(s, m);
  if (lane == 0) red[wid] = s;
  __syncthreads();
  float tot = 0.f;
#pragma unroll
  for (int q = 0; q < 8; ++q) tot += red[q];
  const float mean = tot / 512.f;
  __syncthreads();
  float d = x - mean;
  float s2 = d * d;
#pragma unroll
  for (int m = 1; m < 64; m <<= 1) s2 += __shfl_xor(s2, m);
  if (lane == 0) red[wid] = s2;
  __syncthreads();
  float tot2 = 0.f;
#pragma unroll
  for (int q = 0; q < 8; ++q) tot2 += red[q];
  const float stdv = sqrtf(tot2 / 511.f);   // ddof=1
  float msc = (x - mean) / (stdv + H_F);
  msc = fminf(1.f, fmaxf(-1.f, msc));
  marg[t] = MARGIN_F * (1.f + msc);
}

// ---------------------------------------------------------------------------
// Kernel 3: 64-k phases (2 chunks per barrier) — halves sync events vs R11.
// Per phase p: gload A(p+1) -> COMPUTE 64k from buf (16 MFMA; covers pa/pb
// latency) -> vmcnt(4) (pa,pb done; A flying) -> WWRITE both chunk-sets ->
// WLOAD pa,pb (chunks 2p+4,2p+5) -> vmcnt(8) (A done; new W flies across
// barrier) -> barrier. Same pa+pb live set as R11 -> (256,3), no spill.
// A swizzle (row&7)<<4 both sides; W rows padded to 144 B.
// ---------------------------------------------------------------------------
__global__ __launch_bounds__(256, 3) void k_main(const short* __restrict__ Aunit,
                                                 const float* __restrict__ weight,
                                                 const int* __restrict__ labels,
                                                 const float* __restrict__ marg,
                                                 float* __restrict__ partial,
                                                 float* __restrict__ tlogit) {
  __shared__ alignas(16) char As[2][16384];    // [128 rows][128 B] (64 k), swizzled
  __shared__ alignas(16) char Ws[2][18432];    // [128 cls][144 B] (128 data + 16 pad)
  __shared__ float winv[128];

  const int bid = blockIdx.x;
  const int grp = bid >> 5, within = bid & 31;
  const int rt = (within >> 3) & 3;            // 0..3
  const int ct = grp * 8 + (within & 7);
  if (ct >= NT2) return;

  const int tid = threadIdx.x;                 // 0..255
  const int w = tid >> 6, lane = tid & 63;
  const int l31 = lane & 31, lhi = lane >> 5;

  // ---- A gload source (pre-swizzled). Dest linear: w*4096 + i*1024 + lane*16
  //      -> row r = w*32 + i*8 + (lane>>3), kb = (lane&7)*16. (r&7)==(lane>>3)&7
  //      for all i (i*8 ≡ 0 mod 8) -> one swizzled kb for all 4 gloads.
  const int arr = w * 32 + (lane >> 3);
  const int akbs = ((lane & 7) * 16) ^ ((arr & 7) << 4);
  const char* gA = (const char*)Aunit + (size_t)(rt * 128 + arr) * 1024 + akbs;

  // ---- W stage roles: sc8 = class-in-group, su covers 16 B of f32 per chunk ----
  const int sc8 = tid >> 3;        // 0..31
  const int su  = tid & 7;         // 0..7
  const float* wbase0; const float* wbase1; const float* wbase2; const float* wbase3;
  int wdst0, wdst1, wdst2, wdst3;
  {
    int c0 = 0 * 32 + sc8, c1 = 1 * 32 + sc8, c2 = 2 * 32 + sc8, c3 = 3 * 32 + sc8;
    int g0 = ct * 128 + c0; if (g0 > C_NUM - 1) g0 = C_NUM - 1;
    int g1 = ct * 128 + c1; if (g1 > C_NUM - 1) g1 = C_NUM - 1;
    int g2 = ct * 128 + c2; if (g2 > C_NUM - 1) g2 = C_NUM - 1;
    int g3 = ct * 128 + c3; if (g3 > C_NUM - 1) g3 = C_NUM - 1;
    wbase0 = weight + (size_t)g0 * D_EMB + su * 4;
    wbase1 = weight + (size_t)g1 * D_EMB + su * 4;
    wbase2 = weight + (size_t)g2 * D_EMB + su * 4;
    wbase3 = weight + (size_t)g3 * D_EMB + su * 4;
    wdst0 = c0 * 144 + su * 8; wdst1 = c1 * 144 + su * 8;
    wdst2 = c2 * 144 + su * 8; wdst3 = c3 * 144 + su * 8;
  }

  // ---- compute-side LDS offsets ----
  const int xa = (l31 & 7) << 4;               // A read swizzle key (row = w*32+l31)
  const int abase = (w * 32 + l31) * 128;
  const int bb0 = (l31)       * 144;
  const int bb1 = (32 + l31)  * 144;
  const int bb2 = (64 + l31)  * 144;
  const int bb3 = (96 + l31)  * 144;

  f32x16 acc0, acc1, acc2, acc3;
#pragma unroll
  for (int q = 0; q < 16; ++q) { acc0[q] = 0.f; acc1[q] = 0.f; acc2[q] = 0.f; acc3[q] = 0.f; }
  float ssq0 = 0.f, ssq1 = 0.f, ssq2 = 0.f, ssq3 = 0.f;

  f32x4 pa0, pa1, pa2, pa3;   // even-chunk W set
  f32x4 pb0, pb1, pb2, pb3;   // odd-chunk W set

#define WLOAD(R0,R1,R2,R3,OFF) { \
    R0 = *(const f32x4*)(wbase0 + (OFF)); R1 = *(const f32x4*)(wbase1 + (OFF)); \
    R2 = *(const f32x4*)(wbase2 + (OFF)); R3 = *(const f32x4*)(wbase3 + (OFF)); }

#define WWRITE2(BUF) { \
    bf16x4 t0, t1, t2, t3, u0, u1, u2, u3; \
    _Pragma("unroll") \
    for (int e = 0; e < 4; ++e) { \
      t0[e] = f2bf(pa0[e]); t1[e] = f2bf(pa1[e]); t2[e] = f2bf(pa2[e]); t3[e] = f2bf(pa3[e]); \
      u0[e] = f2bf(pb0[e]); u1[e] = f2bf(pb1[e]); u2[e] = f2bf(pb2[e]); u3[e] = f2bf(pb3[e]); } \
    *(bf16x4*)(&Ws[BUF][wdst0]) = t0; *(bf16x4*)(&Ws[BUF][wdst1]) = t1; \
    *(bf16x4*)(&Ws[BUF][wdst2]) = t2; *(bf16x4*)(&Ws[BUF][wdst3]) = t3; \
    *(bf16x4*)(&Ws[BUF][wdst0 + 64]) = u0; *(bf16x4*)(&Ws[BUF][wdst1 + 64]) = u1; \
    *(bf16x4*)(&Ws[BUF][wdst2 + 64]) = u2; *(bf16x4*)(&Ws[BUF][wdst3 + 64]) = u3; }

#define SSQADD2() { ssq0 += sq4(pa0) + sq4(pb0); ssq1 += sq4(pa1) + sq4(pb1); \
                    ssq2 += sq4(pa2) + sq4(pb2); ssq3 += sq4(pa3) + sq4(pb3); }

#define COMPUTE64(BUF) { \
    const char* Ab = As[BUF]; const char* Wb = Ws[BUF]; \
    __builtin_amdgcn_s_setprio(1); \
    _Pragma("unroll") \
    for (int kk = 0; kk < 4; ++kk) { \
      const int kb = kk * 32 + lhi * 16; \
      bf16x8 a  = *(const bf16x8*)(Ab + abase + (kb ^ xa)); \
      bf16x8 b0 = *(const bf16x8*)(Wb + bb0 + kb); \
      bf16x8 b1 = *(const bf16x8*)(Wb + bb1 + kb); \
      bf16x8 b2 = *(const bf16x8*)(Wb + bb2 + kb); \
      bf16x8 b3 = *(const bf16x8*)(Wb + bb3 + kb); \
      acc0 = __builtin_amdgcn_mfma_f32_32x32x16_bf16(a, b0, acc0, 0, 0, 0); \
      acc1 = __builtin_amdgcn_mfma_f32_32x32x16_bf16(a, b1, acc1, 0, 0, 0); \
      acc2 = __builtin_amdgcn_mfma_f32_32x32x16_bf16(a, b2, acc2, 0, 0, 0); \
      acc3 = __builtin_amdgcn_mfma_f32_32x32x16_bf16(a, b3, acc3, 0, 0, 0); \
    } \
    __builtin_amdgcn_s_setprio(0); }

  // ---- prologue ----
  WLOAD(pa0, pa1, pa2, pa3, 0);                // W chunk 0
  WLOAD(pb0, pb1, pb2, pb3, 32);               // W chunk 1
  __builtin_amdgcn_sched_barrier(0);
#pragma unroll
  for (int i = 0; i < 4; ++i)                  // A phase 0 -> As[0]
    gload16(gA + (size_t)i * 8192, &As[0][w * 4096 + i * 1024]);
  __builtin_amdgcn_sched_barrier(0);
  asm volatile("s_waitcnt vmcnt(4)" ::: "memory");   // pa,pb done; A flying
  SSQADD2();
  WWRITE2(0);
  __builtin_amdgcn_sched_barrier(0);
  WLOAD(pa0, pa1, pa2, pa3, 2 * 32);           // W chunk 2
  WLOAD(pb0, pb1, pb2, pb3, 3 * 32);           // W chunk 3
  __builtin_amdgcn_sched_barrier(0);
  asm volatile("s_waitcnt vmcnt(8)" ::: "memory");   // A(0) done; new W flying
  asm volatile("s_waitcnt lgkmcnt(0)" ::: "memory");
  __builtin_amdgcn_s_barrier();
  __builtin_amdgcn_sched_barrier(0);

  // ---- 8 phases of 64 k ----
  for (int p = 0; p < 8; ++p) {
    const int buf = p & 1;
    // 1. stage A(p+1) (clamped; phase 7's write lands in the dead buffer)
    {
      const int ap = (p + 1 > 7) ? 7 : (p + 1);
      const char* src = gA + ap * 128;
#pragma unroll
      for (int i = 0; i < 4; ++i)
        gload16(src + (size_t)i * 8192, &As[buf ^ 1][w * 4096 + i * 1024]);
    }
    __builtin_amdgcn_sched_barrier(0);
    // 2. compute (covers pa/pb latency)
    COMPUTE64(buf);
    // 3. drain pa,pb (chunks 2p+2,2p+3); A(p+1) still flying
    asm volatile("s_waitcnt vmcnt(4)" ::: "memory");
    if (p < 7) { SSQADD2(); }                  // chunks 2..15 exactly once
    WWRITE2(buf ^ 1);
    __builtin_amdgcn_sched_barrier(0);
    // 4. reload pa,pb <- chunks 2p+4, 2p+5 (clamped at tail)
    {
      int ce = 2 * p + 4; if (ce > 15) ce = 15;
      int co = 2 * p + 5; if (co > 15) co = 15;
      WLOAD(pa0, pa1, pa2, pa3, ce * 32);
      WLOAD(pb0, pb1, pb2, pb3, co * 32);
    }
    __builtin_amdgcn_sched_barrier(0);
    // 5. drain A(p+1); new W stays in flight across the barrier
    asm volatile("s_waitcnt vmcnt(8)" ::: "memory");
    asm volatile("s_waitcnt lgkmcnt(0)" ::: "memory");
    __builtin_amdgcn_s_barrier();
    __builtin_amdgcn_sched_barrier(0);
  }

  // ---- per-class 1/||w||: reduce over the 8 su units ----
  {
    float s0 = ssq0, s1 = ssq1, s2 = ssq2, s3 = ssq3;
#pragma unroll
    for (int m = 1; m < 8; m <<= 1) {
      s0 += __shfl_xor(s0, m); s1 += __shfl_xor(s1, m);
      s2 += __shfl_xor(s2, m); s3 += __shfl_xor(s3, m);
    }
    if (su == 0) {
      winv[sc8]      = (s0 > 0.f) ? rsqrtf(s0) : 0.f;
      winv[32 + sc8] = (s1 > 0.f) ? rsqrtf(s1) : 0.f;
      winv[64 + sc8] = (s2 > 0.f) ? rsqrtf(s2) : 0.f;
      winv[96 + sc8] = (s3 > 0.f) ? rsqrtf(s3) : 0.f;
    }
  }
  __syncthreads();

  // ---- epilogue: margin at label, per-row exp sums ----
  // C/D layout: col = lane&31, row = (reg&3) + 8*(reg>>2) + 4*(lane>>5)
  const float wv0 = winv[l31];
  const float wv1 = winv[32 + l31];
  const float wv2 = winv[64 + l31];
  const float wv3 = winv[96 + l31];
  const int cb = ct * 128;
#pragma unroll
  for (int r = 0; r < 16; ++r) {
    const int rowf = (r & 3) + 8 * (r >> 2) + 4 * lhi;
    const int R = rt * 128 + w * 32 + rowf;
    const int lab = labels[R];
    float v = 0.f;
#pragma unroll
    for (int ni = 0; ni < 4; ++ni) {
      const int gcc = cb + ni * 32 + l31;
      const float wv = (ni == 0) ? wv0 : (ni == 1) ? wv1 : (ni == 2) ? wv2 : wv3;
      const float av = (ni == 0) ? acc0[r] : (ni == 1) ? acc1[r] : (ni == 2) ? acc2[r] : acc3[r];
      const float cosv = av * wv;
      float lg = SCALE_F * cosv;
      if (lab == gcc) {
        float ctv = fminf(1.f, fmaxf(-1.f, cosv));
        float lt = SCALE_F * cosf(acosf(ctv) + marg[R]);
        lg = lt;
        tlogit[R] = lt;
      }
      v += (gcc < C_NUM) ? __expf(lg) : 0.f;
    }
    v += __shfl_xor(v, 1);
    v += __shfl_xor(v, 2);
    v += __shfl_xor(v, 4);
    v += __shfl_xor(v, 8);
    v += __shfl_xor(v, 16);
    if (l31 == 0) partial[(size_t)R * PST + ct] = v;   // row-major -> coalesced reduce
  }
#undef WLOAD
#undef WWRITE2
#undef SSQADD2
#undef COMPUTE64
}

// ---------------------------------------------------------------------------
// Kernel 4: per-row reduce (coalesced): term[r] = log(sum_ct partial[r][ct]) - tlogit[r]
// ---------------------------------------------------------------------------
__global__ __launch_bounds__(64) void k_reduce(const float* __restrict__ partial,
                                               const float* __restrict__ tlogit,
                                               float* __restrict__ term) {
  const int r = blockIdx.x;
  const int l = threadIdx.x;
  const float* row = partial + (size_t)r * PST;
  float s = 0.f;
  for (int b = l; b < NT2; b += 64)
    s += row[b];
#pragma unroll
  for (int m = 1; m < 64; m <<= 1) s += __shfl_xor(s, m);
  if (l == 0) term[r] = logf(s) - tlogit[r];
}

// ---------------------------------------------------------------------------
// Kernel 5: loss = mean(term)
// ---------------------------------------------------------------------------
__global__ __launch_bounds__(512) void k_final(const float* __restrict__ term,
                                               float* __restrict__ out) {
  __shared__ float red[8];
  const int t = threadIdx.x;
  const int lane = t & 63, wid = t >> 6;
  float v = term[t];
#pragma unroll
  for (int m = 1; m < 64; m <<= 1) v += __shfl_xor(v, m);
  if (lane == 0) red[wid] = v;
  __syncthreads();
  if (t == 0) {
    float tot = 0.f;
#pragma unroll
    for (int q = 0; q < 8; ++q) tot += red[q];
    out[0] = tot / 512.f;
  }
}

extern "C" void kernel_launch(void* const* d_in, const int* in_sizes, int n_in,
                              void* d_out, int out_size, void* d_ws, size_t ws_size,
                              hipStream_t stream) {
  const float* emb    = (const float*)d_in[0];
  const int*   labels = (const int*)d_in[1];
  const float* weight = (const float*)d_in[2];
  float* out = (float*)d_out;

  char* ws = (char*)d_ws;
  short* Aunit   = (short*)ws;                        // 512*512*2 = 524288 B
  float* norms   = (float*)(ws + 524288);             // 2 KiB
  float* marg    = (float*)(ws + 524288 + 2048);      // 2 KiB
  float* tlog    = (float*)(ws + 524288 + 4096);      // 2 KiB
  float* term    = (float*)(ws + 524288 + 6144);      // 2 KiB
  float* partial = (float*)(ws + 524288 + 8192);      // 512*784*4 = 1605632 B

  k_rownorm<<<N_BATCH, 64, 0, stream>>>(emb, Aunit, norms);
  k_stats<<<1, 512, 0, stream>>>(norms, marg);
  k_main<<<98 * 32, 256, 0, stream>>>(Aunit, weight, labels, marg, partial, tlog);
  k_reduce<<<N_BATCH, 64, 0, stream>>>(partial, tlog, term);
  k_final<<<1, 512, 0, stream>>>(term, out);
}